// Round 14
// baseline (191.987 us; speedup 1.0000x reference)
//
#include <hip/hip_runtime.h>
#include <hip/hip_bf16.h>

// KGAT via on-device CSR (no float atomics):
//   k1 front:  role A (hdot): hdot[n] = emb[n].att_w[0:64]; rb = rel.att_w + b
//              role B (bhist): per-block LDS histogram of head>>8 -> bcnt
//   k2 bscan:  1-block scan of 782 bucket counts -> boff, gcur
//   k3 scatter1: per 6144-edge chunk (512 thr): LDS hist -> LDS scan -> LDS
//              group -> burst copy-out at atomically-reserved ranges
//              packed 4B: (head&255)<<19 | rel<<18 | tail(18b)
//   k4 scatter2: block per bucket; LDS counting sort over 256 head-lows;
//              writes per-head off[] itself and places payload at CSR slots
//   k5 aggr+xform fused: per-head register segment-sum (f32 gathers, x8
//              unroll = 8 in-flight), then tanh(acc @ W^T + b) via shfl.
// LESSONS: (r8) never aggregate via LDS f32 atomics (~700us). (r6/r7) pad
// global atomic counters 1/cache-line. (r4/r5) amortize LDS W-staging via
// grid-stride; watch VGPR. (r10) bf16 gathers FAIL absmax. (r12) fp16
// gathers REGRESS: gather is transaction/latency-bound (L3-resident table,
// 53% L2 hit), not byte-bound. Lever = more outstanding requests, f32 only.

#define DIM 64
#define TMASK 0x3FFFF
#define RBIT (1 << 18)
#define BSH 8            // 256 heads per bucket
#define NBK_MAX 800      // >= ceil(200000/256) = 782
#define CHUNK 6144
#define SCAN_ITEMS 4     // 256*4 = 1024 >= NBK (bscan, 256 thr)
#define S1_ITEMS 2       // 512*2 = 1024 >= NBK (scatter1, 512 thr)

// ---------------- k1: fused hdot (role A) + bucket histogram (role B) ----------------
__global__ __launch_bounds__(256) void kgat_front(
    const float* __restrict__ emb, const float* __restrict__ rel,
    const float* __restrict__ att_w, const float* __restrict__ att_b,
    const int* __restrict__ ei,
    float* __restrict__ hdot, float* __restrict__ rb,
    int* __restrict__ bcnt,
    int n_ent, int n_rel, int E, int nbk, int hblocks) {
  __shared__ int hist[NBK_MAX];
  if ((int)blockIdx.x < hblocks) {
    int gid = blockIdx.x * 256 + threadIdx.x;
    int n = gid >> 4;
    int q = threadIdx.x & 15;
    if (n >= n_ent + n_rel) return;
    float4 v, w;
    if (n < n_ent) {
      v = ((const float4*)emb)[n * 16 + q];
      w = ((const float4*)att_w)[q];
    } else {
      v = ((const float4*)rel)[(n - n_ent) * 16 + q];
      w = ((const float4*)att_w)[16 + q];
    }
    float p = v.x * w.x + v.y * w.y + v.z * w.z + v.w * w.w;
    p += __shfl_xor(p, 1);
    p += __shfl_xor(p, 2);
    p += __shfl_xor(p, 4);
    p += __shfl_xor(p, 8);
    if (q == 0) {
      if (n < n_ent) hdot[n] = p;
      else rb[n - n_ent] = p + att_b[0];
    }
  } else {
    for (int i = threadIdx.x; i < NBK_MAX; i += 256) hist[i] = 0;
    __syncthreads();
    int base = ((int)blockIdx.x - hblocks) * CHUNK;
    for (int i = threadIdx.x; i < CHUNK; i += 256) {
      int e = base + i;
      if (e < E) atomicAdd(&hist[ei[e] >> BSH], 1);
    }
    __syncthreads();
    for (int b = threadIdx.x; b < nbk; b += 256) {
      int c = hist[b];
      if (c) atomicAdd(&bcnt[b << 4], c);  // padded: 1 counter / 64B line
    }
  }
}

// ---------------- k2: 1-block scan of bucket counts ----------------
__global__ __launch_bounds__(256) void kgat_bscan(
    const int* __restrict__ bcnt, int* __restrict__ boff,
    int* __restrict__ gcur, int nbk) {
  __shared__ int sblk[256];
  int v[SCAN_ITEMS];
  int s = 0;
#pragma unroll
  for (int k = 0; k < SCAN_ITEMS; ++k) {
    int idx = threadIdx.x * SCAN_ITEMS + k;
    v[k] = (idx < nbk) ? bcnt[idx << 4] : 0;
    s += v[k];
  }
  sblk[threadIdx.x] = s;
  __syncthreads();
  for (int d = 1; d < 256; d <<= 1) {
    int t = (threadIdx.x >= (unsigned)d) ? sblk[threadIdx.x - d] : 0;
    __syncthreads();
    sblk[threadIdx.x] += t;
    __syncthreads();
  }
  int excl = sblk[threadIdx.x] - s;
#pragma unroll
  for (int k = 0; k < SCAN_ITEMS; ++k) {
    int idx = threadIdx.x * SCAN_ITEMS + k;
    if (idx < nbk) {
      boff[idx] = excl;
      gcur[idx << 4] = excl;
    }
    excl += v[k];
  }
  if (threadIdx.x == 255) boff[nbk] = excl;  // = E
}

// ---------------- k3: binned scatter, 512 threads, burst writes ----------------
__global__ __launch_bounds__(512) void kgat_scatter1(
    const int* __restrict__ ei, const int* __restrict__ et,
    int* __restrict__ gcur, int* __restrict__ stage, int E, int nbk) {
  __shared__ int hist[NBK_MAX];    // counts, then global base
  __shared__ int lstart[NBK_MAX];
  __shared__ int lcur[NBK_MAX];
  __shared__ int sblk[512];
  __shared__ int vals[CHUNK];
  __shared__ unsigned short bid[CHUNK];
  int tid = threadIdx.x;
  int base = blockIdx.x * CHUNK;
  for (int i = tid; i < NBK_MAX; i += 512) hist[i] = 0;
  __syncthreads();
  for (int i = tid; i < CHUNK; i += 512) {
    int e = base + i;
    if (e < E) atomicAdd(&hist[ei[e] >> BSH], 1);
  }
  __syncthreads();
  int v[S1_ITEMS];
  int s = 0;
#pragma unroll
  for (int k = 0; k < S1_ITEMS; ++k) {
    int idx = tid * S1_ITEMS + k;
    v[k] = (idx < nbk) ? hist[idx] : 0;
    s += v[k];
  }
  sblk[tid] = s;
  __syncthreads();
  for (int d = 1; d < 512; d <<= 1) {
    int t = (tid >= d) ? sblk[tid - d] : 0;
    __syncthreads();
    sblk[tid] += t;
    __syncthreads();
  }
  int excl = sblk[tid] - s;
#pragma unroll
  for (int k = 0; k < S1_ITEMS; ++k) {
    int idx = tid * S1_ITEMS + k;
    if (idx < nbk) {
      lstart[idx] = excl;
      lcur[idx] = excl;
    }
    excl += v[k];
  }
  __syncthreads();
  for (int b = tid; b < nbk; b += 512) {
    int c = hist[b];
    hist[b] = c ? atomicAdd(&gcur[b << 4], c) : 0;
  }
  __syncthreads();
  for (int i = tid; i < CHUNK; i += 512) {
    int e = base + i;
    if (e < E) {
      int h = ei[e];
      int t = ei[E + e];
      int r = et[e];
      int b = h >> BSH;
      int pos = atomicAdd(&lcur[b], 1);
      vals[pos] = t | (r << 18) | ((h & 255) << 19);
      bid[pos] = (unsigned short)b;
    }
  }
  __syncthreads();
  int cc = E - base;
  if (cc > CHUNK) cc = CHUNK;
  for (int p = tid; p < cc; p += 512) {
    int b = bid[p];
    stage[hist[b] + (p - lstart[b])] = vals[p];
  }
}

// ---------------- k4: in-bucket counting sort; writes off[] + payload ----------------
__global__ __launch_bounds__(256) void kgat_scatter2(
    const int* __restrict__ stage, const int* __restrict__ boff,
    int* __restrict__ off, int* __restrict__ payload) {
  __shared__ int hist[256];
  __shared__ int sc[256];
  __shared__ int lcur[256];
  int b = blockIdx.x;
  int tid = threadIdx.x;
  int s0 = boff[b], s1 = boff[b + 1];
  hist[tid] = 0;
  __syncthreads();
  for (int p = s0 + tid; p < s1; p += 256)
    atomicAdd(&hist[(stage[p] >> 19) & 255], 1);
  __syncthreads();
  int c = hist[tid];
  sc[tid] = c;
  __syncthreads();
  for (int d = 1; d < 256; d <<= 1) {
    int t = (tid >= d) ? sc[tid - d] : 0;
    __syncthreads();
    sc[tid] += t;
    __syncthreads();
  }
  int basep = s0 + sc[tid] - c;   // exclusive start for head (b<<8)+tid
  off[(b << 8) + tid] = basep;
  lcur[tid] = basep;
  __syncthreads();
  for (int p = s0 + tid; p < s1; p += 256) {
    int vv = stage[p];
    int pos = atomicAdd(&lcur[(vv >> 19) & 255], 1);
    payload[pos] = vv;
  }
}

// ---------------- k5: segment-sum (8 gathers in flight) + fused transform ----------------
__global__ __launch_bounds__(256) void kgat_aggr_fused(
    const int* __restrict__ off, const int* __restrict__ payload,
    const float* __restrict__ emb, const float* __restrict__ hdot,
    const float* __restrict__ rb, const float* __restrict__ Ww,
    const float* __restrict__ Wb, float* __restrict__ out, int n) {
  __shared__ float Ws[64][68];  // Ws[i][j] = Ww[j][i]
  for (int idx = threadIdx.x; idx < 64 * 64; idx += 256) {
    int j = idx >> 6, i = idx & 63;
    Ws[i][j] = Ww[idx];
  }
  __syncthreads();
  int q = threadIdx.x & 15;
  int grp = threadIdx.x >> 4;
  int lanebase = (threadIdx.x & 63) & ~15;
  int stride = gridDim.x * 16;
  float r0 = rb[0], r1 = rb[1];
  float4 bb = ((const float4*)Wb)[q];
  const float4* emb4 = (const float4*)emb;
  for (int h = blockIdx.x * 16 + grp; h < n; h += stride) {
    int p = off[h];
    int p1 = off[h + 1];
    float hd = hdot[h];
    float sc0 = 1.0f / (1.0f + __expf(-(hd + r0)));
    float sc1 = 1.0f / (1.0f + __expf(-(hd + r1)));
    float4 acc = make_float4(0.f, 0.f, 0.f, 0.f);
    // 8 gathers in flight
    for (; p + 8 <= p1; p += 8) {
      int v0 = payload[p + 0], v1 = payload[p + 1];
      int v2 = payload[p + 2], v3 = payload[p + 3];
      int v4 = payload[p + 4], v5 = payload[p + 5];
      int v6 = payload[p + 6], v7 = payload[p + 7];
      float4 t0 = emb4[(v0 & TMASK) * 16 + q];
      float4 t1 = emb4[(v1 & TMASK) * 16 + q];
      float4 t2 = emb4[(v2 & TMASK) * 16 + q];
      float4 t3 = emb4[(v3 & TMASK) * 16 + q];
      float4 t4 = emb4[(v4 & TMASK) * 16 + q];
      float4 t5 = emb4[(v5 & TMASK) * 16 + q];
      float4 t6 = emb4[(v6 & TMASK) * 16 + q];
      float4 t7 = emb4[(v7 & TMASK) * 16 + q];
      float s0 = (v0 & RBIT) ? sc1 : sc0;
      float s1 = (v1 & RBIT) ? sc1 : sc0;
      float s2 = (v2 & RBIT) ? sc1 : sc0;
      float s3 = (v3 & RBIT) ? sc1 : sc0;
      float s4 = (v4 & RBIT) ? sc1 : sc0;
      float s5 = (v5 & RBIT) ? sc1 : sc0;
      float s6 = (v6 & RBIT) ? sc1 : sc0;
      float s7 = (v7 & RBIT) ? sc1 : sc0;
      acc.x = fmaf(s0, t0.x, acc.x); acc.y = fmaf(s0, t0.y, acc.y);
      acc.z = fmaf(s0, t0.z, acc.z); acc.w = fmaf(s0, t0.w, acc.w);
      acc.x = fmaf(s1, t1.x, acc.x); acc.y = fmaf(s1, t1.y, acc.y);
      acc.z = fmaf(s1, t1.z, acc.z); acc.w = fmaf(s1, t1.w, acc.w);
      acc.x = fmaf(s2, t2.x, acc.x); acc.y = fmaf(s2, t2.y, acc.y);
      acc.z = fmaf(s2, t2.z, acc.z); acc.w = fmaf(s2, t2.w, acc.w);
      acc.x = fmaf(s3, t3.x, acc.x); acc.y = fmaf(s3, t3.y, acc.y);
      acc.z = fmaf(s3, t3.z, acc.z); acc.w = fmaf(s3, t3.w, acc.w);
      acc.x = fmaf(s4, t4.x, acc.x); acc.y = fmaf(s4, t4.y, acc.y);
      acc.z = fmaf(s4, t4.z, acc.z); acc.w = fmaf(s4, t4.w, acc.w);
      acc.x = fmaf(s5, t5.x, acc.x); acc.y = fmaf(s5, t5.y, acc.y);
      acc.z = fmaf(s5, t5.z, acc.z); acc.w = fmaf(s5, t5.w, acc.w);
      acc.x = fmaf(s6, t6.x, acc.x); acc.y = fmaf(s6, t6.y, acc.y);
      acc.z = fmaf(s6, t6.z, acc.z); acc.w = fmaf(s6, t6.w, acc.w);
      acc.x = fmaf(s7, t7.x, acc.x); acc.y = fmaf(s7, t7.y, acc.y);
      acc.z = fmaf(s7, t7.z, acc.z); acc.w = fmaf(s7, t7.w, acc.w);
    }
    for (; p + 4 <= p1; p += 4) {
      int v0 = payload[p + 0], v1 = payload[p + 1];
      int v2 = payload[p + 2], v3 = payload[p + 3];
      float4 t0 = emb4[(v0 & TMASK) * 16 + q];
      float4 t1 = emb4[(v1 & TMASK) * 16 + q];
      float4 t2 = emb4[(v2 & TMASK) * 16 + q];
      float4 t3 = emb4[(v3 & TMASK) * 16 + q];
      float s0 = (v0 & RBIT) ? sc1 : sc0;
      float s1 = (v1 & RBIT) ? sc1 : sc0;
      float s2 = (v2 & RBIT) ? sc1 : sc0;
      float s3 = (v3 & RBIT) ? sc1 : sc0;
      acc.x = fmaf(s0, t0.x, acc.x); acc.y = fmaf(s0, t0.y, acc.y);
      acc.z = fmaf(s0, t0.z, acc.z); acc.w = fmaf(s0, t0.w, acc.w);
      acc.x = fmaf(s1, t1.x, acc.x); acc.y = fmaf(s1, t1.y, acc.y);
      acc.z = fmaf(s1, t1.z, acc.z); acc.w = fmaf(s1, t1.w, acc.w);
      acc.x = fmaf(s2, t2.x, acc.x); acc.y = fmaf(s2, t2.y, acc.y);
      acc.z = fmaf(s2, t2.z, acc.z); acc.w = fmaf(s2, t2.w, acc.w);
      acc.x = fmaf(s3, t3.x, acc.x); acc.y = fmaf(s3, t3.y, acc.y);
      acc.z = fmaf(s3, t3.z, acc.z); acc.w = fmaf(s3, t3.w, acc.w);
    }
    for (; p < p1; ++p) {
      int v0 = payload[p];
      float s0 = (v0 & RBIT) ? sc1 : sc0;
      float4 t0 = emb4[(v0 & TMASK) * 16 + q];
      acc.x = fmaf(s0, t0.x, acc.x); acc.y = fmaf(s0, t0.y, acc.y);
      acc.z = fmaf(s0, t0.z, acc.z); acc.w = fmaf(s0, t0.w, acc.w);
    }
    // fused transform: o = tanh(W @ acc + b), acc distributed over 16 lanes
    float4 o = bb;
#pragma unroll 4
    for (int j = 0; j < 16; ++j) {
      float a0 = __shfl(acc.x, lanebase + j);
      float a1 = __shfl(acc.y, lanebase + j);
      float a2 = __shfl(acc.z, lanebase + j);
      float a3 = __shfl(acc.w, lanebase + j);
      float4 w0 = *(const float4*)&Ws[4 * j + 0][4 * q];
      float4 w1 = *(const float4*)&Ws[4 * j + 1][4 * q];
      float4 w2 = *(const float4*)&Ws[4 * j + 2][4 * q];
      float4 w3 = *(const float4*)&Ws[4 * j + 3][4 * q];
      o.x = fmaf(a0, w0.x, o.x); o.y = fmaf(a0, w0.y, o.y);
      o.z = fmaf(a0, w0.z, o.z); o.w = fmaf(a0, w0.w, o.w);
      o.x = fmaf(a1, w1.x, o.x); o.y = fmaf(a1, w1.y, o.y);
      o.z = fmaf(a1, w1.z, o.z); o.w = fmaf(a1, w1.w, o.w);
      o.x = fmaf(a2, w2.x, o.x); o.y = fmaf(a2, w2.y, o.y);
      o.z = fmaf(a2, w2.z, o.z); o.w = fmaf(a2, w2.w, o.w);
      o.x = fmaf(a3, w3.x, o.x); o.y = fmaf(a3, w3.y, o.y);
      o.z = fmaf(a3, w3.z, o.z); o.w = fmaf(a3, w3.w, o.w);
    }
    o.x = tanhf(o.x); o.y = tanhf(o.y); o.z = tanhf(o.z); o.w = tanhf(o.w);
    ((float4*)out)[h * 16 + q] = o;
  }
}

extern "C" void kernel_launch(void* const* d_in, const int* in_sizes, int n_in,
                              void* d_out, int out_size, void* d_ws, size_t ws_size,
                              hipStream_t stream) {
  const int* edge_index = (const int*)d_in[0];
  const int* edge_type  = (const int*)d_in[1];
  const float* entity_emb   = (const float*)d_in[2];
  const float* relation_emb = (const float*)d_in[3];
  const float* att_w = (const float*)d_in[4];
  const float* att_b = (const float*)d_in[5];
  const float* W_w   = (const float*)d_in[6];
  const float* W_b   = (const float*)d_in[7];
  float* out = (float*)d_out;

  const int E     = in_sizes[0] / 2;
  const int N_ENT = in_sizes[2] / DIM;
  const int N_REL = in_sizes[3] / DIM;
  const int NBK   = (N_ENT + 255) >> BSH;

  // ws layout (4B units)
  int* w32 = (int*)d_ws;
  float* hdot = (float*)w32;                    // N_ENT
  float* rb   = (float*)(w32 + N_ENT);          // 8
  int*   bcnt = w32 + N_ENT + 8;                // NBK*16 (padded, 1/line)
  int*   boff = bcnt + NBK * 16;                // NBK+1
  int*   gcur = boff + NBK + 1;                 // NBK*16 (padded, 1/line)
  int*   off  = gcur + NBK * 16;                // NBK*256 + 1
  int*   stage   = off + NBK * 256 + 1;         // E
  int*   payload = stage + E;                   // E

  hipMemsetAsync(bcnt, 0, (size_t)NBK * 16 * sizeof(int), stream);

  int hblocks = ((N_ENT + N_REL) * 16 + 255) / 256;
  int eblocks = (E + CHUNK - 1) / CHUNK;
  kgat_front<<<hblocks + eblocks, 256, 0, stream>>>(
      entity_emb, relation_emb, att_w, att_b, edge_index,
      hdot, rb, bcnt, N_ENT, N_REL, E, NBK, hblocks);
  kgat_bscan<<<1, 256, 0, stream>>>(bcnt, boff, gcur, NBK);
  kgat_scatter1<<<eblocks, 512, 0, stream>>>(edge_index, edge_type, gcur, stage, E, NBK);
  kgat_scatter2<<<NBK, 256, 0, stream>>>(stage, boff, off, payload);
  kgat_aggr_fused<<<2048, 256, 0, stream>>>(off, payload, entity_emb, hdot, rb,
                                            W_w, W_b, out, N_ENT);
}

// Round 15
// 187.082 us; speedup vs baseline: 1.0262x; 1.0262x over previous
//
#include <hip/hip_runtime.h>
#include <hip/hip_bf16.h>

// KGAT via on-device CSR (no float atomics):
//   k1 front:  role A (hdot): hdot[n] = emb[n].att_w[0:64]; rb = rel.att_w + b
//              role B (bhist): per-block LDS histogram of head>>8 -> bcnt
//   k2 bscan:  1-block scan of 782 bucket counts -> boff, gcur
//   k3 scatter1: per 6144-edge chunk (512 thr): LDS hist -> LDS scan -> LDS
//              group -> burst copy-out at atomically-reserved ranges
//              packed 4B: (head&255)<<19 | rel<<18 | tail(18b)
//   k4 aggr2:  block per bucket (512 thr): in-LDS counting sort of the
//              bucket's stage slice, then per-group (16 lanes, 8 heads each)
//              register segment-sum (f32 gathers, x4 unroll) + fused
//              tanh(acc @ W^T + b) shfl transform. Replaces scatter2+aggr.
// LESSONS: (r8) never aggregate via LDS f32 atomics (~700us). (r6/r7) pad
// global atomic counters 1/cache-line. (r4/r5) amortize LDS W-staging; watch
// VGPR. (r10) bf16 gathers FAIL absmax. (r12) fp16 gathers REGRESS and
// (r14) 8-deep unroll REGRESSES (segments avg ~10): gather engine is pinned
// at ~2.5TB/s random 256B L3 fills with 4-deep + ~21 waves/CU. Keep 4-deep.

#define DIM 64
#define TMASK 0x3FFFF
#define RBIT (1 << 18)
#define BSH 8            // 256 heads per bucket
#define NBK_MAX 800      // >= ceil(200000/256) = 782
#define CHUNK 6144
#define SCAN_ITEMS 4     // 256*4 = 1024 >= NBK (bscan, 256 thr)
#define S1_ITEMS 2       // 512*2 = 1024 >= NBK (scatter1, 512 thr)
#define SCAP 4608        // aggr2 LDS slice cap (avg bucket 2560, +40 sigma)

// ---------------- k1: fused hdot (role A) + bucket histogram (role B) ----------------
__global__ __launch_bounds__(256) void kgat_front(
    const float* __restrict__ emb, const float* __restrict__ rel,
    const float* __restrict__ att_w, const float* __restrict__ att_b,
    const int* __restrict__ ei,
    float* __restrict__ hdot, float* __restrict__ rb,
    int* __restrict__ bcnt,
    int n_ent, int n_rel, int E, int nbk, int hblocks) {
  __shared__ int hist[NBK_MAX];
  if ((int)blockIdx.x < hblocks) {
    int gid = blockIdx.x * 256 + threadIdx.x;
    int n = gid >> 4;
    int q = threadIdx.x & 15;
    if (n >= n_ent + n_rel) return;
    float4 v, w;
    if (n < n_ent) {
      v = ((const float4*)emb)[n * 16 + q];
      w = ((const float4*)att_w)[q];
    } else {
      v = ((const float4*)rel)[(n - n_ent) * 16 + q];
      w = ((const float4*)att_w)[16 + q];
    }
    float p = v.x * w.x + v.y * w.y + v.z * w.z + v.w * w.w;
    p += __shfl_xor(p, 1);
    p += __shfl_xor(p, 2);
    p += __shfl_xor(p, 4);
    p += __shfl_xor(p, 8);
    if (q == 0) {
      if (n < n_ent) hdot[n] = p;
      else rb[n - n_ent] = p + att_b[0];
    }
  } else {
    for (int i = threadIdx.x; i < NBK_MAX; i += 256) hist[i] = 0;
    __syncthreads();
    int base = ((int)blockIdx.x - hblocks) * CHUNK;
    for (int i = threadIdx.x; i < CHUNK; i += 256) {
      int e = base + i;
      if (e < E) atomicAdd(&hist[ei[e] >> BSH], 1);
    }
    __syncthreads();
    for (int b = threadIdx.x; b < nbk; b += 256) {
      int c = hist[b];
      if (c) atomicAdd(&bcnt[b << 4], c);  // padded: 1 counter / 64B line
    }
  }
}

// ---------------- k2: 1-block scan of bucket counts ----------------
__global__ __launch_bounds__(256) void kgat_bscan(
    const int* __restrict__ bcnt, int* __restrict__ boff,
    int* __restrict__ gcur, int nbk) {
  __shared__ int sblk[256];
  int v[SCAN_ITEMS];
  int s = 0;
#pragma unroll
  for (int k = 0; k < SCAN_ITEMS; ++k) {
    int idx = threadIdx.x * SCAN_ITEMS + k;
    v[k] = (idx < nbk) ? bcnt[idx << 4] : 0;
    s += v[k];
  }
  sblk[threadIdx.x] = s;
  __syncthreads();
  for (int d = 1; d < 256; d <<= 1) {
    int t = (threadIdx.x >= (unsigned)d) ? sblk[threadIdx.x - d] : 0;
    __syncthreads();
    sblk[threadIdx.x] += t;
    __syncthreads();
  }
  int excl = sblk[threadIdx.x] - s;
#pragma unroll
  for (int k = 0; k < SCAN_ITEMS; ++k) {
    int idx = threadIdx.x * SCAN_ITEMS + k;
    if (idx < nbk) {
      boff[idx] = excl;
      gcur[idx << 4] = excl;
    }
    excl += v[k];
  }
  if (threadIdx.x == 255) boff[nbk] = excl;  // = E
}

// ---------------- k3: binned scatter, 512 threads, burst writes ----------------
__global__ __launch_bounds__(512) void kgat_scatter1(
    const int* __restrict__ ei, const int* __restrict__ et,
    int* __restrict__ gcur, int* __restrict__ stage, int E, int nbk) {
  __shared__ int hist[NBK_MAX];    // counts, then global base
  __shared__ int lstart[NBK_MAX];
  __shared__ int lcur[NBK_MAX];
  __shared__ int sblk[512];
  __shared__ int vals[CHUNK];
  __shared__ unsigned short bid[CHUNK];
  int tid = threadIdx.x;
  int base = blockIdx.x * CHUNK;
  for (int i = tid; i < NBK_MAX; i += 512) hist[i] = 0;
  __syncthreads();
  for (int i = tid; i < CHUNK; i += 512) {
    int e = base + i;
    if (e < E) atomicAdd(&hist[ei[e] >> BSH], 1);
  }
  __syncthreads();
  int v[S1_ITEMS];
  int s = 0;
#pragma unroll
  for (int k = 0; k < S1_ITEMS; ++k) {
    int idx = tid * S1_ITEMS + k;
    v[k] = (idx < nbk) ? hist[idx] : 0;
    s += v[k];
  }
  sblk[tid] = s;
  __syncthreads();
  for (int d = 1; d < 512; d <<= 1) {
    int t = (tid >= d) ? sblk[tid - d] : 0;
    __syncthreads();
    sblk[tid] += t;
    __syncthreads();
  }
  int excl = sblk[tid] - s;
#pragma unroll
  for (int k = 0; k < S1_ITEMS; ++k) {
    int idx = tid * S1_ITEMS + k;
    if (idx < nbk) {
      lstart[idx] = excl;
      lcur[idx] = excl;
    }
    excl += v[k];
  }
  __syncthreads();
  for (int b = tid; b < nbk; b += 512) {
    int c = hist[b];
    hist[b] = c ? atomicAdd(&gcur[b << 4], c) : 0;
  }
  __syncthreads();
  for (int i = tid; i < CHUNK; i += 512) {
    int e = base + i;
    if (e < E) {
      int h = ei[e];
      int t = ei[E + e];
      int r = et[e];
      int b = h >> BSH;
      int pos = atomicAdd(&lcur[b], 1);
      vals[pos] = t | (r << 18) | ((h & 255) << 19);
      bid[pos] = (unsigned short)b;
    }
  }
  __syncthreads();
  int cc = E - base;
  if (cc > CHUNK) cc = CHUNK;
  for (int p = tid; p < cc; p += 512) {
    int b = bid[p];
    stage[hist[b] + (p - lstart[b])] = vals[p];
  }
}

// ---------------- k4: fused in-bucket sort + segment-sum + transform ----------------
__global__ __launch_bounds__(512) void kgat_aggr2(
    const int* __restrict__ boff, const int* __restrict__ stage,
    const float* __restrict__ emb, const float* __restrict__ hdot,
    const float* __restrict__ rb, const float* __restrict__ Ww,
    const float* __restrict__ Wb, float* __restrict__ out, int n) {
  __shared__ float Ws[64][68];  // Ws[i][j] = Ww[j][i]
  __shared__ int svals[SCAP];
  __shared__ int hist[256];
  __shared__ int sc[256];
  __shared__ int lcur[256];
  int tid = threadIdx.x;
  int b = blockIdx.x;
  for (int idx = tid; idx < 64 * 64; idx += 512) {
    int j = idx >> 6, i = idx & 63;
    Ws[i][j] = Ww[idx];
  }
  int q = tid & 15;
  int grp = tid >> 4;                 // 0..31
  int lanebase = (tid & 63) & ~15;
  int h0 = b << 8;
  int s0 = boff[b], s1 = boff[b + 1];
  int m = s1 - s0;
  float r0 = rb[0], r1 = rb[1];
  const float4* emb4 = (const float4*)emb;
  float4 bb;
  bb = ((const float4*)Wb)[q];

  if (m <= SCAP) {
    // --- fast path: counting sort of the slice into LDS ---
    if (tid < 256) hist[tid] = 0;
    __syncthreads();
    for (int i = tid; i < m; i += 512) {
      int v = stage[s0 + i];
      atomicAdd(&hist[(v >> 19) & 255], 1);
    }
    __syncthreads();
    int c = 0;
    if (tid < 256) { c = hist[tid]; sc[tid] = c; }
    __syncthreads();
    for (int d = 1; d < 256; d <<= 1) {
      int t = 0;
      if (tid < 256 && tid >= d) t = sc[tid - d];
      __syncthreads();
      if (tid < 256) sc[tid] += t;   // inclusive scan
      __syncthreads();
    }
    if (tid < 256) lcur[tid] = sc[tid] - c;  // exclusive start
    __syncthreads();
    for (int i = tid; i < m; i += 512) {
      int v = stage[s0 + i];         // L2-hot re-read
      int pos = atomicAdd(&lcur[(v >> 19) & 255], 1);
      svals[pos] = v;
    }
    __syncthreads();
    // --- per-group: 8 heads each, edges from LDS ---
    for (int hl = grp; hl < 256; hl += 32) {
      int h = h0 + hl;
      if (h >= n) break;             // uniform within group
      int jend = sc[hl];
      int j = jend - hist[hl];
      float hd = hdot[h];
      float sA = 1.0f / (1.0f + __expf(-(hd + r0)));
      float sB = 1.0f / (1.0f + __expf(-(hd + r1)));
      float4 acc = make_float4(0.f, 0.f, 0.f, 0.f);
      for (; j + 4 <= jend; j += 4) {
        int v0 = svals[j + 0];
        int v1 = svals[j + 1];
        int v2 = svals[j + 2];
        int v3 = svals[j + 3];
        float4 t0 = emb4[(v0 & TMASK) * 16 + q];
        float4 t1 = emb4[(v1 & TMASK) * 16 + q];
        float4 t2 = emb4[(v2 & TMASK) * 16 + q];
        float4 t3 = emb4[(v3 & TMASK) * 16 + q];
        float s0f = (v0 & RBIT) ? sB : sA;
        float s1f = (v1 & RBIT) ? sB : sA;
        float s2f = (v2 & RBIT) ? sB : sA;
        float s3f = (v3 & RBIT) ? sB : sA;
        acc.x = fmaf(s0f, t0.x, acc.x); acc.y = fmaf(s0f, t0.y, acc.y);
        acc.z = fmaf(s0f, t0.z, acc.z); acc.w = fmaf(s0f, t0.w, acc.w);
        acc.x = fmaf(s1f, t1.x, acc.x); acc.y = fmaf(s1f, t1.y, acc.y);
        acc.z = fmaf(s1f, t1.z, acc.z); acc.w = fmaf(s1f, t1.w, acc.w);
        acc.x = fmaf(s2f, t2.x, acc.x); acc.y = fmaf(s2f, t2.y, acc.y);
        acc.z = fmaf(s2f, t2.z, acc.z); acc.w = fmaf(s2f, t2.w, acc.w);
        acc.x = fmaf(s3f, t3.x, acc.x); acc.y = fmaf(s3f, t3.y, acc.y);
        acc.z = fmaf(s3f, t3.z, acc.z); acc.w = fmaf(s3f, t3.w, acc.w);
      }
      for (; j < jend; ++j) {
        int v0 = svals[j];
        float s0f = (v0 & RBIT) ? sB : sA;
        float4 t0 = emb4[(v0 & TMASK) * 16 + q];
        acc.x = fmaf(s0f, t0.x, acc.x); acc.y = fmaf(s0f, t0.y, acc.y);
        acc.z = fmaf(s0f, t0.z, acc.z); acc.w = fmaf(s0f, t0.w, acc.w);
      }
      // fused transform: o = tanh(W @ acc + b)
      float4 o = bb;
#pragma unroll 4
      for (int jj = 0; jj < 16; ++jj) {
        float a0 = __shfl(acc.x, lanebase + jj);
        float a1 = __shfl(acc.y, lanebase + jj);
        float a2 = __shfl(acc.z, lanebase + jj);
        float a3 = __shfl(acc.w, lanebase + jj);
        float4 w0 = *(const float4*)&Ws[4 * jj + 0][4 * q];
        float4 w1 = *(const float4*)&Ws[4 * jj + 1][4 * q];
        float4 w2 = *(const float4*)&Ws[4 * jj + 2][4 * q];
        float4 w3 = *(const float4*)&Ws[4 * jj + 3][4 * q];
        o.x = fmaf(a0, w0.x, o.x); o.y = fmaf(a0, w0.y, o.y);
        o.z = fmaf(a0, w0.z, o.z); o.w = fmaf(a0, w0.w, o.w);
        o.x = fmaf(a1, w1.x, o.x); o.y = fmaf(a1, w1.y, o.y);
        o.z = fmaf(a1, w1.z, o.z); o.w = fmaf(a1, w1.w, o.w);
        o.x = fmaf(a2, w2.x, o.x); o.y = fmaf(a2, w2.y, o.y);
        o.z = fmaf(a2, w2.z, o.z); o.w = fmaf(a2, w2.w, o.w);
        o.x = fmaf(a3, w3.x, o.x); o.y = fmaf(a3, w3.y, o.y);
        o.z = fmaf(a3, w3.z, o.z); o.w = fmaf(a3, w3.w, o.w);
      }
      o.x = tanhf(o.x); o.y = tanhf(o.y); o.z = tanhf(o.z); o.w = tanhf(o.w);
      ((float4*)out)[h * 16 + q] = o;
    }
  } else {
    // --- fallback (degenerate bucket > SCAP edges): global filter per head ---
    __syncthreads();
    for (int hl = grp; hl < 256; hl += 32) {
      int h = h0 + hl;
      if (h >= n) break;
      float hd = hdot[h];
      float sA = 1.0f / (1.0f + __expf(-(hd + r0)));
      float sB = 1.0f / (1.0f + __expf(-(hd + r1)));
      float4 acc = make_float4(0.f, 0.f, 0.f, 0.f);
      for (int p = s0; p < s1; ++p) {
        int v = stage[p];
        if (((v >> 19) & 255) == hl) {
          float s0f = (v & RBIT) ? sB : sA;
          float4 t0 = emb4[(v & TMASK) * 16 + q];
          acc.x = fmaf(s0f, t0.x, acc.x); acc.y = fmaf(s0f, t0.y, acc.y);
          acc.z = fmaf(s0f, t0.z, acc.z); acc.w = fmaf(s0f, t0.w, acc.w);
        }
      }
      float4 o = bb;
#pragma unroll 4
      for (int jj = 0; jj < 16; ++jj) {
        float a0 = __shfl(acc.x, lanebase + jj);
        float a1 = __shfl(acc.y, lanebase + jj);
        float a2 = __shfl(acc.z, lanebase + jj);
        float a3 = __shfl(acc.w, lanebase + jj);
        float4 w0 = *(const float4*)&Ws[4 * jj + 0][4 * q];
        float4 w1 = *(const float4*)&Ws[4 * jj + 1][4 * q];
        float4 w2 = *(const float4*)&Ws[4 * jj + 2][4 * q];
        float4 w3 = *(const float4*)&Ws[4 * jj + 3][4 * q];
        o.x = fmaf(a0, w0.x, o.x); o.y = fmaf(a0, w0.y, o.y);
        o.z = fmaf(a0, w0.z, o.z); o.w = fmaf(a0, w0.w, o.w);
        o.x = fmaf(a1, w1.x, o.x); o.y = fmaf(a1, w1.y, o.y);
        o.z = fmaf(a1, w1.z, o.z); o.w = fmaf(a1, w1.w, o.w);
        o.x = fmaf(a2, w2.x, o.x); o.y = fmaf(a2, w2.y, o.y);
        o.z = fmaf(a2, w2.z, o.z); o.w = fmaf(a2, w2.w, o.w);
        o.x = fmaf(a3, w3.x, o.x); o.y = fmaf(a3, w3.y, o.y);
        o.z = fmaf(a3, w3.z, o.z); o.w = fmaf(a3, w3.w, o.w);
      }
      o.x = tanhf(o.x); o.y = tanhf(o.y); o.z = tanhf(o.z); o.w = tanhf(o.w);
      ((float4*)out)[h * 16 + q] = o;
    }
  }
}

extern "C" void kernel_launch(void* const* d_in, const int* in_sizes, int n_in,
                              void* d_out, int out_size, void* d_ws, size_t ws_size,
                              hipStream_t stream) {
  const int* edge_index = (const int*)d_in[0];
  const int* edge_type  = (const int*)d_in[1];
  const float* entity_emb   = (const float*)d_in[2];
  const float* relation_emb = (const float*)d_in[3];
  const float* att_w = (const float*)d_in[4];
  const float* att_b = (const float*)d_in[5];
  const float* W_w   = (const float*)d_in[6];
  const float* W_b   = (const float*)d_in[7];
  float* out = (float*)d_out;

  const int E     = in_sizes[0] / 2;
  const int N_ENT = in_sizes[2] / DIM;
  const int N_REL = in_sizes[3] / DIM;
  const int NBK   = (N_ENT + 255) >> BSH;

  // ws layout (4B units)
  int* w32 = (int*)d_ws;
  float* hdot = (float*)w32;                    // N_ENT
  float* rb   = (float*)(w32 + N_ENT);          // 8
  int*   bcnt = w32 + N_ENT + 8;                // NBK*16 (padded, 1/line)
  int*   boff = bcnt + NBK * 16;                // NBK+1
  int*   gcur = boff + NBK + 1;                 // NBK*16 (padded, 1/line)
  int*   stage= gcur + NBK * 16;                // E

  hipMemsetAsync(bcnt, 0, (size_t)NBK * 16 * sizeof(int), stream);

  int hblocks = ((N_ENT + N_REL) * 16 + 255) / 256;
  int eblocks = (E + CHUNK - 1) / CHUNK;
  kgat_front<<<hblocks + eblocks, 256, 0, stream>>>(
      entity_emb, relation_emb, att_w, att_b, edge_index,
      hdot, rb, bcnt, N_ENT, N_REL, E, NBK, hblocks);
  kgat_bscan<<<1, 256, 0, stream>>>(bcnt, boff, gcur, NBK);
  kgat_scatter1<<<eblocks, 512, 0, stream>>>(edge_index, edge_type, gcur, stage, E, NBK);
  kgat_aggr2<<<NBK, 512, 0, stream>>>(boff, stage, entity_emb, hdot, rb,
                                      W_w, W_b, out, N_ENT);
}

// Round 16
// 176.258 us; speedup vs baseline: 1.0892x; 1.0614x over previous
//
#include <hip/hip_runtime.h>
#include <hip/hip_bf16.h>

// KGAT via on-device CSR (no float atomics):
//   k1 front:  role A (hdot): hdot[n] = emb[n].att_w[0:64]; rb = rel.att_w + b
//              role B (bhist): per-block LDS histogram of head>>8 -> bcnt
//   k2 bscan:  1-block scan of 782 bucket counts -> boff, gcur
//   k3 scatter1: per 6144-edge chunk (512 thr): LDS hist -> LDS scan -> LDS
//              group -> burst copy-out at atomically-reserved ranges
//              packed 4B: (head&255)<<19 | rel<<18 | tail(18b)
//   k4 scatter2: block per bucket (512 thr), SINGLE-PASS: stage slice ->
//              LDS svals (+hist during staging) -> scan -> off[] + payload
//   k5 aggr+xform fused: per-head register segment-sum (f32 gathers, x4
//              unroll), then tanh(acc @ W^T + b) via 16-lane shfl scheme.
// LESSONS: (r8) never aggregate via LDS f32 atomics (~700us). (r6/r7) pad
// global atomic counters 1/cache-line. (r4/r5) amortize LDS W-staging via
// grid-stride; watch VGPR. (r10) bf16 gathers FAIL absmax. (r12) fp16
// gathers REGRESS (transaction-bound, not byte-bound). (r14) 8-deep unroll
// REGRESSES (segments avg ~10; occupancy loss). (r15) fusing the bucket
// sort into the gather kernel REGRESSES (LDS+grid kills residency): keep
// the gather kernel lean at ~21 waves/CU; aggr ~97us is structural.

#define DIM 64
#define TMASK 0x3FFFF
#define RBIT (1 << 18)
#define BSH 8            // 256 heads per bucket
#define NBK_MAX 800      // >= ceil(200000/256) = 782
#define CHUNK 6144
#define SCAN_ITEMS 4     // 256*4 = 1024 >= NBK (bscan, 256 thr)
#define S1_ITEMS 2       // 512*2 = 1024 >= NBK (scatter1, 512 thr)
#define SCAP 4608        // scatter2 LDS slice cap (avg bucket 2560, +40 sigma)

// ---------------- k1: fused hdot (role A) + bucket histogram (role B) ----------------
__global__ __launch_bounds__(256) void kgat_front(
    const float* __restrict__ emb, const float* __restrict__ rel,
    const float* __restrict__ att_w, const float* __restrict__ att_b,
    const int* __restrict__ ei,
    float* __restrict__ hdot, float* __restrict__ rb,
    int* __restrict__ bcnt,
    int n_ent, int n_rel, int E, int nbk, int hblocks) {
  __shared__ int hist[NBK_MAX];
  if ((int)blockIdx.x < hblocks) {
    int gid = blockIdx.x * 256 + threadIdx.x;
    int n = gid >> 4;
    int q = threadIdx.x & 15;
    if (n >= n_ent + n_rel) return;
    float4 v, w;
    if (n < n_ent) {
      v = ((const float4*)emb)[n * 16 + q];
      w = ((const float4*)att_w)[q];
    } else {
      v = ((const float4*)rel)[(n - n_ent) * 16 + q];
      w = ((const float4*)att_w)[16 + q];
    }
    float p = v.x * w.x + v.y * w.y + v.z * w.z + v.w * w.w;
    p += __shfl_xor(p, 1);
    p += __shfl_xor(p, 2);
    p += __shfl_xor(p, 4);
    p += __shfl_xor(p, 8);
    if (q == 0) {
      if (n < n_ent) hdot[n] = p;
      else rb[n - n_ent] = p + att_b[0];
    }
  } else {
    for (int i = threadIdx.x; i < NBK_MAX; i += 256) hist[i] = 0;
    __syncthreads();
    int base = ((int)blockIdx.x - hblocks) * CHUNK;
    for (int i = threadIdx.x; i < CHUNK; i += 256) {
      int e = base + i;
      if (e < E) atomicAdd(&hist[ei[e] >> BSH], 1);
    }
    __syncthreads();
    for (int b = threadIdx.x; b < nbk; b += 256) {
      int c = hist[b];
      if (c) atomicAdd(&bcnt[b << 4], c);  // padded: 1 counter / 64B line
    }
  }
}

// ---------------- k2: 1-block scan of bucket counts ----------------
__global__ __launch_bounds__(256) void kgat_bscan(
    const int* __restrict__ bcnt, int* __restrict__ boff,
    int* __restrict__ gcur, int nbk) {
  __shared__ int sblk[256];
  int v[SCAN_ITEMS];
  int s = 0;
#pragma unroll
  for (int k = 0; k < SCAN_ITEMS; ++k) {
    int idx = threadIdx.x * SCAN_ITEMS + k;
    v[k] = (idx < nbk) ? bcnt[idx << 4] : 0;
    s += v[k];
  }
  sblk[threadIdx.x] = s;
  __syncthreads();
  for (int d = 1; d < 256; d <<= 1) {
    int t = (threadIdx.x >= (unsigned)d) ? sblk[threadIdx.x - d] : 0;
    __syncthreads();
    sblk[threadIdx.x] += t;
    __syncthreads();
  }
  int excl = sblk[threadIdx.x] - s;
#pragma unroll
  for (int k = 0; k < SCAN_ITEMS; ++k) {
    int idx = threadIdx.x * SCAN_ITEMS + k;
    if (idx < nbk) {
      boff[idx] = excl;
      gcur[idx << 4] = excl;
    }
    excl += v[k];
  }
  if (threadIdx.x == 255) boff[nbk] = excl;  // = E
}

// ---------------- k3: binned scatter, 512 threads, burst writes ----------------
__global__ __launch_bounds__(512) void kgat_scatter1(
    const int* __restrict__ ei, const int* __restrict__ et,
    int* __restrict__ gcur, int* __restrict__ stage, int E, int nbk) {
  __shared__ int hist[NBK_MAX];    // counts, then global base
  __shared__ int lstart[NBK_MAX];
  __shared__ int lcur[NBK_MAX];
  __shared__ int sblk[512];
  __shared__ int vals[CHUNK];
  __shared__ unsigned short bid[CHUNK];
  int tid = threadIdx.x;
  int base = blockIdx.x * CHUNK;
  for (int i = tid; i < NBK_MAX; i += 512) hist[i] = 0;
  __syncthreads();
  for (int i = tid; i < CHUNK; i += 512) {
    int e = base + i;
    if (e < E) atomicAdd(&hist[ei[e] >> BSH], 1);
  }
  __syncthreads();
  int v[S1_ITEMS];
  int s = 0;
#pragma unroll
  for (int k = 0; k < S1_ITEMS; ++k) {
    int idx = tid * S1_ITEMS + k;
    v[k] = (idx < nbk) ? hist[idx] : 0;
    s += v[k];
  }
  sblk[tid] = s;
  __syncthreads();
  for (int d = 1; d < 512; d <<= 1) {
    int t = (tid >= d) ? sblk[tid - d] : 0;
    __syncthreads();
    sblk[tid] += t;
    __syncthreads();
  }
  int excl = sblk[tid] - s;
#pragma unroll
  for (int k = 0; k < S1_ITEMS; ++k) {
    int idx = tid * S1_ITEMS + k;
    if (idx < nbk) {
      lstart[idx] = excl;
      lcur[idx] = excl;
    }
    excl += v[k];
  }
  __syncthreads();
  for (int b = tid; b < nbk; b += 512) {
    int c = hist[b];
    hist[b] = c ? atomicAdd(&gcur[b << 4], c) : 0;
  }
  __syncthreads();
  for (int i = tid; i < CHUNK; i += 512) {
    int e = base + i;
    if (e < E) {
      int h = ei[e];
      int t = ei[E + e];
      int r = et[e];
      int b = h >> BSH;
      int pos = atomicAdd(&lcur[b], 1);
      vals[pos] = t | (r << 18) | ((h & 255) << 19);
      bid[pos] = (unsigned short)b;
    }
  }
  __syncthreads();
  int cc = E - base;
  if (cc > CHUNK) cc = CHUNK;
  for (int p = tid; p < cc; p += 512) {
    int b = bid[p];
    stage[hist[b] + (p - lstart[b])] = vals[p];
  }
}

// ---------------- k4: single-pass in-bucket counting sort ----------------
__global__ __launch_bounds__(512) void kgat_scatter2(
    const int* __restrict__ stage, const int* __restrict__ boff,
    int* __restrict__ off, int* __restrict__ payload) {
  __shared__ int svals[SCAP];
  __shared__ int hist[256];
  __shared__ int sc[256];
  __shared__ int lcur[256];
  int b = blockIdx.x;
  int tid = threadIdx.x;
  int s0 = boff[b], s1 = boff[b + 1];
  int m = s1 - s0;
  if (tid < 256) hist[tid] = 0;
  __syncthreads();
  if (m <= SCAP) {
    // stage slice -> LDS (coalesced), histogram in the same pass
    for (int i = tid; i < m; i += 512) {
      int v = stage[s0 + i];
      svals[i] = v;
      atomicAdd(&hist[(v >> 19) & 255], 1);
    }
    __syncthreads();
    int c = 0;
    if (tid < 256) { c = hist[tid]; sc[tid] = c; }
    __syncthreads();
    for (int d = 1; d < 256; d <<= 1) {
      int t = 0;
      if (tid < 256 && tid >= d) t = sc[tid - d];
      __syncthreads();
      if (tid < 256) sc[tid] += t;  // inclusive scan
      __syncthreads();
    }
    if (tid < 256) {
      int basep = s0 + sc[tid] - c;  // exclusive start for head (b<<8)+tid
      off[(b << 8) + tid] = basep;
      lcur[tid] = basep;
    }
    __syncthreads();
    for (int i = tid; i < m; i += 512) {
      int v = svals[i];
      int pos = atomicAdd(&lcur[(v >> 19) & 255], 1);
      payload[pos] = v;
    }
  } else {
    // fallback (degenerate bucket): two-pass global
    for (int p = s0 + tid; p < s1; p += 512)
      atomicAdd(&hist[(stage[p] >> 19) & 255], 1);
    __syncthreads();
    int c = 0;
    if (tid < 256) { c = hist[tid]; sc[tid] = c; }
    __syncthreads();
    for (int d = 1; d < 256; d <<= 1) {
      int t = 0;
      if (tid < 256 && tid >= d) t = sc[tid - d];
      __syncthreads();
      if (tid < 256) sc[tid] += t;
      __syncthreads();
    }
    if (tid < 256) {
      int basep = s0 + sc[tid] - c;
      off[(b << 8) + tid] = basep;
      lcur[tid] = basep;
    }
    __syncthreads();
    for (int p = s0 + tid; p < s1; p += 512) {
      int v = stage[p];
      int pos = atomicAdd(&lcur[(v >> 19) & 255], 1);
      payload[pos] = v;
    }
  }
}

// ---------------- k5: segment-sum + fused tanh(acc @ W^T + b) ----------------
__global__ __launch_bounds__(256) void kgat_aggr_fused(
    const int* __restrict__ off, const int* __restrict__ payload,
    const float* __restrict__ emb, const float* __restrict__ hdot,
    const float* __restrict__ rb, const float* __restrict__ Ww,
    const float* __restrict__ Wb, float* __restrict__ out, int n) {
  __shared__ float Ws[64][68];  // Ws[i][j] = Ww[j][i]
  for (int idx = threadIdx.x; idx < 64 * 64; idx += 256) {
    int j = idx >> 6, i = idx & 63;
    Ws[i][j] = Ww[idx];
  }
  __syncthreads();
  int q = threadIdx.x & 15;
  int grp = threadIdx.x >> 4;
  int lanebase = (threadIdx.x & 63) & ~15;
  int stride = gridDim.x * 16;
  float r0 = rb[0], r1 = rb[1];
  float4 bb = ((const float4*)Wb)[q];
  const float4* emb4 = (const float4*)emb;
  for (int h = blockIdx.x * 16 + grp; h < n; h += stride) {
    int p = off[h];
    int p1 = off[h + 1];
    float hd = hdot[h];
    float sc0 = 1.0f / (1.0f + __expf(-(hd + r0)));
    float sc1 = 1.0f / (1.0f + __expf(-(hd + r1)));
    float4 acc = make_float4(0.f, 0.f, 0.f, 0.f);
    for (; p + 4 <= p1; p += 4) {
      int v0 = payload[p + 0];
      int v1 = payload[p + 1];
      int v2 = payload[p + 2];
      int v3 = payload[p + 3];
      float4 t0 = emb4[(v0 & TMASK) * 16 + q];
      float4 t1 = emb4[(v1 & TMASK) * 16 + q];
      float4 t2 = emb4[(v2 & TMASK) * 16 + q];
      float4 t3 = emb4[(v3 & TMASK) * 16 + q];
      float s0 = (v0 & RBIT) ? sc1 : sc0;
      float s1 = (v1 & RBIT) ? sc1 : sc0;
      float s2 = (v2 & RBIT) ? sc1 : sc0;
      float s3 = (v3 & RBIT) ? sc1 : sc0;
      acc.x = fmaf(s0, t0.x, acc.x); acc.y = fmaf(s0, t0.y, acc.y);
      acc.z = fmaf(s0, t0.z, acc.z); acc.w = fmaf(s0, t0.w, acc.w);
      acc.x = fmaf(s1, t1.x, acc.x); acc.y = fmaf(s1, t1.y, acc.y);
      acc.z = fmaf(s1, t1.z, acc.z); acc.w = fmaf(s1, t1.w, acc.w);
      acc.x = fmaf(s2, t2.x, acc.x); acc.y = fmaf(s2, t2.y, acc.y);
      acc.z = fmaf(s2, t2.z, acc.z); acc.w = fmaf(s2, t2.w, acc.w);
      acc.x = fmaf(s3, t3.x, acc.x); acc.y = fmaf(s3, t3.y, acc.y);
      acc.z = fmaf(s3, t3.z, acc.z); acc.w = fmaf(s3, t3.w, acc.w);
    }
    for (; p < p1; ++p) {
      int v0 = payload[p];
      float s0 = (v0 & RBIT) ? sc1 : sc0;
      float4 t0 = emb4[(v0 & TMASK) * 16 + q];
      acc.x = fmaf(s0, t0.x, acc.x); acc.y = fmaf(s0, t0.y, acc.y);
      acc.z = fmaf(s0, t0.z, acc.z); acc.w = fmaf(s0, t0.w, acc.w);
    }
    // fused transform: o = tanh(W @ acc + b), acc distributed over 16 lanes
    float4 o = bb;
#pragma unroll 4
    for (int j = 0; j < 16; ++j) {
      float a0 = __shfl(acc.x, lanebase + j);
      float a1 = __shfl(acc.y, lanebase + j);
      float a2 = __shfl(acc.z, lanebase + j);
      float a3 = __shfl(acc.w, lanebase + j);
      float4 w0 = *(const float4*)&Ws[4 * j + 0][4 * q];
      float4 w1 = *(const float4*)&Ws[4 * j + 1][4 * q];
      float4 w2 = *(const float4*)&Ws[4 * j + 2][4 * q];
      float4 w3 = *(const float4*)&Ws[4 * j + 3][4 * q];
      o.x = fmaf(a0, w0.x, o.x); o.y = fmaf(a0, w0.y, o.y);
      o.z = fmaf(a0, w0.z, o.z); o.w = fmaf(a0, w0.w, o.w);
      o.x = fmaf(a1, w1.x, o.x); o.y = fmaf(a1, w1.y, o.y);
      o.z = fmaf(a1, w1.z, o.z); o.w = fmaf(a1, w1.w, o.w);
      o.x = fmaf(a2, w2.x, o.x); o.y = fmaf(a2, w2.y, o.y);
      o.z = fmaf(a2, w2.z, o.z); o.w = fmaf(a2, w2.w, o.w);
      o.x = fmaf(a3, w3.x, o.x); o.y = fmaf(a3, w3.y, o.y);
      o.z = fmaf(a3, w3.z, o.z); o.w = fmaf(a3, w3.w, o.w);
    }
    o.x = tanhf(o.x); o.y = tanhf(o.y); o.z = tanhf(o.z); o.w = tanhf(o.w);
    ((float4*)out)[h * 16 + q] = o;
  }
}

extern "C" void kernel_launch(void* const* d_in, const int* in_sizes, int n_in,
                              void* d_out, int out_size, void* d_ws, size_t ws_size,
                              hipStream_t stream) {
  const int* edge_index = (const int*)d_in[0];
  const int* edge_type  = (const int*)d_in[1];
  const float* entity_emb   = (const float*)d_in[2];
  const float* relation_emb = (const float*)d_in[3];
  const float* att_w = (const float*)d_in[4];
  const float* att_b = (const float*)d_in[5];
  const float* W_w   = (const float*)d_in[6];
  const float* W_b   = (const float*)d_in[7];
  float* out = (float*)d_out;

  const int E     = in_sizes[0] / 2;
  const int N_ENT = in_sizes[2] / DIM;
  const int N_REL = in_sizes[3] / DIM;
  const int NBK   = (N_ENT + 255) >> BSH;

  // ws layout (4B units)
  int* w32 = (int*)d_ws;
  float* hdot = (float*)w32;                    // N_ENT
  float* rb   = (float*)(w32 + N_ENT);          // 8
  int*   bcnt = w32 + N_ENT + 8;                // NBK*16 (padded, 1/line)
  int*   boff = bcnt + NBK * 16;                // NBK+1
  int*   gcur = boff + NBK + 1;                 // NBK*16 (padded, 1/line)
  int*   off  = gcur + NBK * 16;                // NBK*256 + 1
  int*   stage   = off + NBK * 256 + 1;         // E
  int*   payload = stage + E;                   // E

  hipMemsetAsync(bcnt, 0, (size_t)NBK * 16 * sizeof(int), stream);

  int hblocks = ((N_ENT + N_REL) * 16 + 255) / 256;
  int eblocks = (E + CHUNK - 1) / CHUNK;
  kgat_front<<<hblocks + eblocks, 256, 0, stream>>>(
      entity_emb, relation_emb, att_w, att_b, edge_index,
      hdot, rb, bcnt, N_ENT, N_REL, E, NBK, hblocks);
  kgat_bscan<<<1, 256, 0, stream>>>(bcnt, boff, gcur, NBK);
  kgat_scatter1<<<eblocks, 512, 0, stream>>>(edge_index, edge_type, gcur, stage, E, NBK);
  kgat_scatter2<<<NBK, 512, 0, stream>>>(stage, boff, off, payload);
  kgat_aggr_fused<<<2048, 256, 0, stream>>>(off, payload, entity_emb, hdot, rb,
                                            W_w, W_b, out, N_ENT);
}

// Round 17
// 173.680 us; speedup vs baseline: 1.1054x; 1.0148x over previous
//
#include <hip/hip_runtime.h>
#include <hip/hip_bf16.h>

// KGAT via on-device CSR (no float atomics):
//   k1 front:  role A (hdot): hdot[n] = emb[n].att_w[0:64]; rb = rel.att_w + b
//              role B (bhist): per-block LDS histogram of head>>8 -> bcnt
//   k2 bscan:  1-block scan of 782 bucket counts -> boff, gcur
//   k3 scatter1: per 6144-edge chunk (512 thr, 12 edges/thread IN REGISTERS,
//              single global read pass): LDS hist -> LDS scan -> LDS group ->
//              burst copy-out at atomically-reserved ranges
//              packed 4B: (head&255)<<19 | rel<<18 | tail(18b)
//   k4 scatter2: block per bucket (512 thr), SINGLE-PASS: stage slice ->
//              LDS svals (+hist during staging) -> scan -> off[] + payload
//   k5 aggr+xform fused: per-head register segment-sum (f32 gathers, x4
//              unroll), then tanh(acc @ W^T + b) via 16-lane shfl scheme.
// LESSONS: (r8) never aggregate via LDS f32 atomics (~700us). (r6/r7) pad
// global atomic counters 1/cache-line. (r4/r5) amortize LDS W-staging via
// grid-stride; watch VGPR. (r10) bf16 gathers FAIL absmax. (r12) fp16
// gathers REGRESS (transaction-bound, not byte-bound). (r14) 8-deep unroll
// REGRESSES (segments avg ~10; occupancy loss). (r15) fusing the bucket
// sort into the gather kernel REGRESSES (LDS+grid kills residency): keep
// the gather kernel lean; aggr ~97us is the structural gather floor.

#define DIM 64
#define TMASK 0x3FFFF
#define RBIT (1 << 18)
#define BSH 8            // 256 heads per bucket
#define NBK_MAX 800      // >= ceil(200000/256) = 782
#define CHUNK 6144
#define EPT 12           // edges per thread in scatter1 (CHUNK/512)
#define SCAN_ITEMS 4     // 256*4 = 1024 >= NBK (bscan, 256 thr)
#define S1_ITEMS 2       // 512*2 = 1024 >= NBK (scatter1, 512 thr)
#define SCAP 4608        // scatter2 LDS slice cap (avg bucket 2560, +40 sigma)

// ---------------- k1: fused hdot (role A) + bucket histogram (role B) ----------------
__global__ __launch_bounds__(256) void kgat_front(
    const float* __restrict__ emb, const float* __restrict__ rel,
    const float* __restrict__ att_w, const float* __restrict__ att_b,
    const int* __restrict__ ei,
    float* __restrict__ hdot, float* __restrict__ rb,
    int* __restrict__ bcnt,
    int n_ent, int n_rel, int E, int nbk, int hblocks) {
  __shared__ int hist[NBK_MAX];
  if ((int)blockIdx.x < hblocks) {
    int gid = blockIdx.x * 256 + threadIdx.x;
    int n = gid >> 4;
    int q = threadIdx.x & 15;
    if (n >= n_ent + n_rel) return;
    float4 v, w;
    if (n < n_ent) {
      v = ((const float4*)emb)[n * 16 + q];
      w = ((const float4*)att_w)[q];
    } else {
      v = ((const float4*)rel)[(n - n_ent) * 16 + q];
      w = ((const float4*)att_w)[16 + q];
    }
    float p = v.x * w.x + v.y * w.y + v.z * w.z + v.w * w.w;
    p += __shfl_xor(p, 1);
    p += __shfl_xor(p, 2);
    p += __shfl_xor(p, 4);
    p += __shfl_xor(p, 8);
    if (q == 0) {
      if (n < n_ent) hdot[n] = p;
      else rb[n - n_ent] = p + att_b[0];
    }
  } else {
    for (int i = threadIdx.x; i < NBK_MAX; i += 256) hist[i] = 0;
    __syncthreads();
    int base = ((int)blockIdx.x - hblocks) * CHUNK;
    for (int i = threadIdx.x; i < CHUNK; i += 256) {
      int e = base + i;
      if (e < E) atomicAdd(&hist[ei[e] >> BSH], 1);
    }
    __syncthreads();
    for (int b = threadIdx.x; b < nbk; b += 256) {
      int c = hist[b];
      if (c) atomicAdd(&bcnt[b << 4], c);  // padded: 1 counter / 64B line
    }
  }
}

// ---------------- k2: 1-block scan of bucket counts ----------------
__global__ __launch_bounds__(256) void kgat_bscan(
    const int* __restrict__ bcnt, int* __restrict__ boff,
    int* __restrict__ gcur, int nbk) {
  __shared__ int sblk[256];
  int v[SCAN_ITEMS];
  int s = 0;
#pragma unroll
  for (int k = 0; k < SCAN_ITEMS; ++k) {
    int idx = threadIdx.x * SCAN_ITEMS + k;
    v[k] = (idx < nbk) ? bcnt[idx << 4] : 0;
    s += v[k];
  }
  sblk[threadIdx.x] = s;
  __syncthreads();
  for (int d = 1; d < 256; d <<= 1) {
    int t = (threadIdx.x >= (unsigned)d) ? sblk[threadIdx.x - d] : 0;
    __syncthreads();
    sblk[threadIdx.x] += t;
    __syncthreads();
  }
  int excl = sblk[threadIdx.x] - s;
#pragma unroll
  for (int k = 0; k < SCAN_ITEMS; ++k) {
    int idx = threadIdx.x * SCAN_ITEMS + k;
    if (idx < nbk) {
      boff[idx] = excl;
      gcur[idx << 4] = excl;
    }
    excl += v[k];
  }
  if (threadIdx.x == 255) boff[nbk] = excl;  // = E
}

// ---------------- k3: binned scatter, single global read pass ----------------
__global__ __launch_bounds__(512) void kgat_scatter1(
    const int* __restrict__ ei, const int* __restrict__ et,
    int* __restrict__ gcur, int* __restrict__ stage, int E, int nbk) {
  __shared__ int hist[NBK_MAX];    // counts, then global base
  __shared__ int lstart[NBK_MAX];
  __shared__ int lcur[NBK_MAX];
  __shared__ int sblk[512];
  __shared__ int vals[CHUNK];
  __shared__ unsigned short bid[CHUNK];
  int tid = threadIdx.x;
  int base = blockIdx.x * CHUNK;
  // phase 1: single global read pass; pack vals + bucket into registers
  int mval[EPT];
  int mb[EPT];
  for (int i = tid; i < NBK_MAX; i += 512) hist[i] = 0;
  __syncthreads();
#pragma unroll
  for (int k = 0; k < EPT; ++k) {
    int e = base + tid + k * 512;
    mb[k] = -1;
    if (e < E) {
      int h = ei[e];
      int t = ei[E + e];
      int r = et[e];
      mval[k] = t | (r << 18) | ((h & 255) << 19);
      mb[k] = h >> BSH;
      atomicAdd(&hist[mb[k]], 1);
    }
  }
  __syncthreads();
  // phase 2: LDS scan (512 thr x 2 items) -> lstart/lcur
  int v[S1_ITEMS];
  int s = 0;
#pragma unroll
  for (int k = 0; k < S1_ITEMS; ++k) {
    int idx = tid * S1_ITEMS + k;
    v[k] = (idx < nbk) ? hist[idx] : 0;
    s += v[k];
  }
  sblk[tid] = s;
  __syncthreads();
  for (int d = 1; d < 512; d <<= 1) {
    int t = (tid >= d) ? sblk[tid - d] : 0;
    __syncthreads();
    sblk[tid] += t;
    __syncthreads();
  }
  int excl = sblk[tid] - s;
#pragma unroll
  for (int k = 0; k < S1_ITEMS; ++k) {
    int idx = tid * S1_ITEMS + k;
    if (idx < nbk) {
      lstart[idx] = excl;
      lcur[idx] = excl;
    }
    excl += v[k];
  }
  __syncthreads();
  // phase 3: reserve global ranges (counts still in hist) -> hist := gbase
  for (int b = tid; b < nbk; b += 512) {
    int c = hist[b];
    hist[b] = c ? atomicAdd(&gcur[b << 4], c) : 0;
  }
  __syncthreads();
  // phase 4: group register-held edges into LDS
#pragma unroll
  for (int k = 0; k < EPT; ++k) {
    if (mb[k] >= 0) {
      int pos = atomicAdd(&lcur[mb[k]], 1);
      vals[pos] = mval[k];
      bid[pos] = (unsigned short)mb[k];
    }
  }
  __syncthreads();
  // phase 5: burst copy-out (consecutive p -> consecutive global addrs per run)
  int cc = E - base;
  if (cc > CHUNK) cc = CHUNK;
  for (int p = tid; p < cc; p += 512) {
    int b = bid[p];
    stage[hist[b] + (p - lstart[b])] = vals[p];
  }
}

// ---------------- k4: single-pass in-bucket counting sort ----------------
__global__ __launch_bounds__(512) void kgat_scatter2(
    const int* __restrict__ stage, const int* __restrict__ boff,
    int* __restrict__ off, int* __restrict__ payload) {
  __shared__ int svals[SCAP];
  __shared__ int hist[256];
  __shared__ int sc[256];
  __shared__ int lcur[256];
  int b = blockIdx.x;
  int tid = threadIdx.x;
  int s0 = boff[b], s1 = boff[b + 1];
  int m = s1 - s0;
  if (tid < 256) hist[tid] = 0;
  __syncthreads();
  if (m <= SCAP) {
    for (int i = tid; i < m; i += 512) {
      int v = stage[s0 + i];
      svals[i] = v;
      atomicAdd(&hist[(v >> 19) & 255], 1);
    }
    __syncthreads();
    int c = 0;
    if (tid < 256) { c = hist[tid]; sc[tid] = c; }
    __syncthreads();
    for (int d = 1; d < 256; d <<= 1) {
      int t = 0;
      if (tid < 256 && tid >= d) t = sc[tid - d];
      __syncthreads();
      if (tid < 256) sc[tid] += t;  // inclusive scan
      __syncthreads();
    }
    if (tid < 256) {
      int basep = s0 + sc[tid] - c;  // exclusive start for head (b<<8)+tid
      off[(b << 8) + tid] = basep;
      lcur[tid] = basep;
    }
    __syncthreads();
    for (int i = tid; i < m; i += 512) {
      int v = svals[i];
      int pos = atomicAdd(&lcur[(v >> 19) & 255], 1);
      payload[pos] = v;
    }
  } else {
    for (int p = s0 + tid; p < s1; p += 512)
      atomicAdd(&hist[(stage[p] >> 19) & 255], 1);
    __syncthreads();
    int c = 0;
    if (tid < 256) { c = hist[tid]; sc[tid] = c; }
    __syncthreads();
    for (int d = 1; d < 256; d <<= 1) {
      int t = 0;
      if (tid < 256 && tid >= d) t = sc[tid - d];
      __syncthreads();
      if (tid < 256) sc[tid] += t;
      __syncthreads();
    }
    if (tid < 256) {
      int basep = s0 + sc[tid] - c;
      off[(b << 8) + tid] = basep;
      lcur[tid] = basep;
    }
    __syncthreads();
    for (int p = s0 + tid; p < s1; p += 512) {
      int v = stage[p];
      int pos = atomicAdd(&lcur[(v >> 19) & 255], 1);
      payload[pos] = v;
    }
  }
}

// ---------------- k5: segment-sum + fused tanh(acc @ W^T + b) ----------------
__global__ __launch_bounds__(256) void kgat_aggr_fused(
    const int* __restrict__ off, const int* __restrict__ payload,
    const float* __restrict__ emb, const float* __restrict__ hdot,
    const float* __restrict__ rb, const float* __restrict__ Ww,
    const float* __restrict__ Wb, float* __restrict__ out, int n) {
  __shared__ float Ws[64][68];  // Ws[i][j] = Ww[j][i]
  for (int idx = threadIdx.x; idx < 64 * 64; idx += 256) {
    int j = idx >> 6, i = idx & 63;
    Ws[i][j] = Ww[idx];
  }
  __syncthreads();
  int q = threadIdx.x & 15;
  int grp = threadIdx.x >> 4;
  int lanebase = (threadIdx.x & 63) & ~15;
  int stride = gridDim.x * 16;
  float r0 = rb[0], r1 = rb[1];
  float4 bb = ((const float4*)Wb)[q];
  const float4* emb4 = (const float4*)emb;
  for (int h = blockIdx.x * 16 + grp; h < n; h += stride) {
    int p = off[h];
    int p1 = off[h + 1];
    float hd = hdot[h];
    float sc0 = 1.0f / (1.0f + __expf(-(hd + r0)));
    float sc1 = 1.0f / (1.0f + __expf(-(hd + r1)));
    float4 acc = make_float4(0.f, 0.f, 0.f, 0.f);
    for (; p + 4 <= p1; p += 4) {
      int v0 = payload[p + 0];
      int v1 = payload[p + 1];
      int v2 = payload[p + 2];
      int v3 = payload[p + 3];
      float4 t0 = emb4[(v0 & TMASK) * 16 + q];
      float4 t1 = emb4[(v1 & TMASK) * 16 + q];
      float4 t2 = emb4[(v2 & TMASK) * 16 + q];
      float4 t3 = emb4[(v3 & TMASK) * 16 + q];
      float s0 = (v0 & RBIT) ? sc1 : sc0;
      float s1 = (v1 & RBIT) ? sc1 : sc0;
      float s2 = (v2 & RBIT) ? sc1 : sc0;
      float s3 = (v3 & RBIT) ? sc1 : sc0;
      acc.x = fmaf(s0, t0.x, acc.x); acc.y = fmaf(s0, t0.y, acc.y);
      acc.z = fmaf(s0, t0.z, acc.z); acc.w = fmaf(s0, t0.w, acc.w);
      acc.x = fmaf(s1, t1.x, acc.x); acc.y = fmaf(s1, t1.y, acc.y);
      acc.z = fmaf(s1, t1.z, acc.z); acc.w = fmaf(s1, t1.w, acc.w);
      acc.x = fmaf(s2, t2.x, acc.x); acc.y = fmaf(s2, t2.y, acc.y);
      acc.z = fmaf(s2, t2.z, acc.z); acc.w = fmaf(s2, t2.w, acc.w);
      acc.x = fmaf(s3, t3.x, acc.x); acc.y = fmaf(s3, t3.y, acc.y);
      acc.z = fmaf(s3, t3.z, acc.z); acc.w = fmaf(s3, t3.w, acc.w);
    }
    for (; p < p1; ++p) {
      int v0 = payload[p];
      float s0 = (v0 & RBIT) ? sc1 : sc0;
      float4 t0 = emb4[(v0 & TMASK) * 16 + q];
      acc.x = fmaf(s0, t0.x, acc.x); acc.y = fmaf(s0, t0.y, acc.y);
      acc.z = fmaf(s0, t0.z, acc.z); acc.w = fmaf(s0, t0.w, acc.w);
    }
    // fused transform: o = tanh(W @ acc + b), acc distributed over 16 lanes
    float4 o = bb;
#pragma unroll 4
    for (int j = 0; j < 16; ++j) {
      float a0 = __shfl(acc.x, lanebase + j);
      float a1 = __shfl(acc.y, lanebase + j);
      float a2 = __shfl(acc.z, lanebase + j);
      float a3 = __shfl(acc.w, lanebase + j);
      float4 w0 = *(const float4*)&Ws[4 * j + 0][4 * q];
      float4 w1 = *(const float4*)&Ws[4 * j + 1][4 * q];
      float4 w2 = *(const float4*)&Ws[4 * j + 2][4 * q];
      float4 w3 = *(const float4*)&Ws[4 * j + 3][4 * q];
      o.x = fmaf(a0, w0.x, o.x); o.y = fmaf(a0, w0.y, o.y);
      o.z = fmaf(a0, w0.z, o.z); o.w = fmaf(a0, w0.w, o.w);
      o.x = fmaf(a1, w1.x, o.x); o.y = fmaf(a1, w1.y, o.y);
      o.z = fmaf(a1, w1.z, o.z); o.w = fmaf(a1, w1.w, o.w);
      o.x = fmaf(a2, w2.x, o.x); o.y = fmaf(a2, w2.y, o.y);
      o.z = fmaf(a2, w2.z, o.z); o.w = fmaf(a2, w2.w, o.w);
      o.x = fmaf(a3, w3.x, o.x); o.y = fmaf(a3, w3.y, o.y);
      o.z = fmaf(a3, w3.z, o.z); o.w = fmaf(a3, w3.w, o.w);
    }
    o.x = tanhf(o.x); o.y = tanhf(o.y); o.z = tanhf(o.z); o.w = tanhf(o.w);
    ((float4*)out)[h * 16 + q] = o;
  }
}

extern "C" void kernel_launch(void* const* d_in, const int* in_sizes, int n_in,
                              void* d_out, int out_size, void* d_ws, size_t ws_size,
                              hipStream_t stream) {
  const int* edge_index = (const int*)d_in[0];
  const int* edge_type  = (const int*)d_in[1];
  const float* entity_emb   = (const float*)d_in[2];
  const float* relation_emb = (const float*)d_in[3];
  const float* att_w = (const float*)d_in[4];
  const float* att_b = (const float*)d_in[5];
  const float* W_w   = (const float*)d_in[6];
  const float* W_b   = (const float*)d_in[7];
  float* out = (float*)d_out;

  const int E     = in_sizes[0] / 2;
  const int N_ENT = in_sizes[2] / DIM;
  const int N_REL = in_sizes[3] / DIM;
  const int NBK   = (N_ENT + 255) >> BSH;

  // ws layout (4B units)
  int* w32 = (int*)d_ws;
  float* hdot = (float*)w32;                    // N_ENT
  float* rb   = (float*)(w32 + N_ENT);          // 8
  int*   bcnt = w32 + N_ENT + 8;                // NBK*16 (padded, 1/line)
  int*   boff = bcnt + NBK * 16;                // NBK+1
  int*   gcur = boff + NBK + 1;                 // NBK*16 (padded, 1/line)
  int*   off  = gcur + NBK * 16;                // NBK*256 + 1
  int*   stage   = off + NBK * 256 + 1;         // E
  int*   payload = stage + E;                   // E

  hipMemsetAsync(bcnt, 0, (size_t)NBK * 16 * sizeof(int), stream);

  int hblocks = ((N_ENT + N_REL) * 16 + 255) / 256;
  int eblocks = (E + CHUNK - 1) / CHUNK;
  kgat_front<<<hblocks + eblocks, 256, 0, stream>>>(
      entity_emb, relation_emb, att_w, att_b, edge_index,
      hdot, rb, bcnt, N_ENT, N_REL, E, NBK, hblocks);
  kgat_bscan<<<1, 256, 0, stream>>>(bcnt, boff, gcur, NBK);
  kgat_scatter1<<<eblocks, 512, 0, stream>>>(edge_index, edge_type, gcur, stage, E, NBK);
  kgat_scatter2<<<NBK, 512, 0, stream>>>(stage, boff, off, payload);
  kgat_aggr_fused<<<2048, 256, 0, stream>>>(off, payload, entity_emb, hdot, rb,
                                            W_w, W_b, out, N_ENT);
}